// Round 1
// baseline (409.955 us; speedup 1.0000x reference)
//
#include <hip/hip_runtime.h>

typedef float f32x4 __attribute__((ext_vector_type(4)));
typedef short s16x8 __attribute__((ext_vector_type(8)));

#define B_SZ 4
#define T_SZ 2048
#define D_SZ 1024
#define NH 16
#define HD 64

// ---------- helpers ----------
__device__ __forceinline__ unsigned short f2b(float f) {
  unsigned int u = __builtin_bit_cast(unsigned int, f);
  unsigned int r = (u + 0x7fffu + ((u >> 16) & 1u)) >> 16;  // RNE
  return (unsigned short)r;
}

__device__ __forceinline__ void gld_lds16(void* lds, const void* g) {
  __builtin_amdgcn_global_load_lds(
      (const __attribute__((address_space(1))) unsigned int*)g,
      (__attribute__((address_space(3))) unsigned int*)lds, 16, 0, 0);
}

// ---------- fp32 -> bf16 cast ----------
__global__ void cast_kernel(const float* __restrict__ in,
                            unsigned short* __restrict__ out, int n4) {
  int i = blockIdx.x * blockDim.x + threadIdx.x;
  if (i < n4) {
    float4 v = reinterpret_cast<const float4*>(in)[i];
    ushort4 o;
    o.x = f2b(v.x); o.y = f2b(v.y); o.z = f2b(v.z); o.w = f2b(v.w);
    reinterpret_cast<ushort4*>(out)[i] = o;
  }
}

// ---------- GEMM: C[M,N] = A[M,K] * W[N,K]^T  (m97-style 128x128 tile) ----------
#define BM 128
#define BN 128
#define BKG 32

template <typename OutT>
__global__ __launch_bounds__(256, 2) void gemm_bt(
    const unsigned short* __restrict__ A,
    const unsigned short* __restrict__ W,
    OutT* __restrict__ C, int M, int N, int K) {
  __shared__ __align__(16) unsigned short As[BM * BKG];
  __shared__ __align__(16) unsigned short Ws[BN * BKG];
  const int tid = threadIdx.x, wid = tid >> 6, lane = tid & 63;
  const int row0 = blockIdx.x * BM, col0 = blockIdx.y * BN;
  const int wr = (wid >> 1) * 64, wc = (wid & 1) * 64;
  const int fr = lane & 15, kg = (lane >> 4) * 8;  // fragment row / k-group (elems)
  f32x4 acc[4][4] = {};

  // staging: chunk c (0..7) covers 16 rows of 64B; lane l -> row c*16+(l>>2), col (l&3)*8
  const int srow = lane >> 2;
  const int scol = (lane & 3) * 8;

  for (int k0 = 0; k0 < K; k0 += BKG) {
    __syncthreads();
#pragma unroll
    for (int i = 0; i < 2; ++i) {
      const int c = wid + 4 * i;
      gld_lds16(&As[c * 512], &A[(row0 + c * 16 + srow) * K + k0 + scol]);
      gld_lds16(&Ws[c * 512], &W[(col0 + c * 16 + srow) * K + k0 + scol]);
    }
    __syncthreads();
    s16x8 af[4], bf[4];
#pragma unroll
    for (int m = 0; m < 4; ++m)
      af[m] = *(const s16x8*)&As[(wr + m * 16 + fr) * BKG + kg];
#pragma unroll
    for (int n = 0; n < 4; ++n)
      bf[n] = *(const s16x8*)&Ws[(wc + n * 16 + fr) * BKG + kg];
#pragma unroll
    for (int m = 0; m < 4; ++m)
#pragma unroll
      for (int n = 0; n < 4; ++n)
        acc[m][n] = __builtin_amdgcn_mfma_f32_16x16x32_bf16(af[m], bf[n], acc[m][n], 0, 0, 0);
  }

  const int crow = row0 + wr + ((lane >> 4) << 2);
  const int ccol = col0 + wc + fr;
#pragma unroll
  for (int m = 0; m < 4; ++m)
#pragma unroll
    for (int n = 0; n < 4; ++n)
#pragma unroll
      for (int r = 0; r < 4; ++r) {
        float v = acc[m][n][r];
        int idx = (crow + m * 16 + r) * N + ccol + n * 16;
        if constexpr (sizeof(OutT) == 2)
          ((unsigned short*)C)[idx] = f2b(v);
        else
          C[idx] = v;
      }
}

// ---------- flash attention (non-causal, full softmax) ----------
// grid: (T/128, B*NH); block 256 (4 waves, 32 q-rows per wave), KV tiles of 64
#define QBLK 128
#define KVB 64

__global__ __launch_bounds__(256, 2) void attn_kernel(
    const unsigned short* __restrict__ Q,
    const unsigned short* __restrict__ K,
    const unsigned short* __restrict__ V,
    unsigned short* __restrict__ O) {
  __shared__ __align__(16) char Kl[KVB * 128];      // [kv][d] rows 128B, XOR-swizzled
  __shared__ __align__(16) char Vl[HD * 128];       // [d][kv] rows 128B, XOR-swizzled
  __shared__ __align__(16) char Pl[4][32 * 128];    // per-wave P [q][kv], XOR-swizzled

  const int tid = threadIdx.x, wid = tid >> 6, lane = tid & 63;
  const int fr = lane & 15, kg = (lane >> 4) * 8;
  const int b = blockIdx.y >> 4, h = blockIdx.y & 15;
  const int q0 = blockIdx.x * QBLK;
  const int base = (b * T_SZ) * D_SZ + h * HD;
  const int wq = wid * 32;

  // Q fragments in registers (A-operand): row fr, d = ks*32 + kg .. +8
  s16x8 qf[2][2];
#pragma unroll
  for (int m = 0; m < 2; ++m)
#pragma unroll
    for (int ks = 0; ks < 2; ++ks)
      qf[m][ks] = *(const s16x8*)&Q[base + (q0 + wq + m * 16 + fr) * D_SZ + ks * 32 + kg];

  f32x4 oacc[2][4] = {};
  float mrow[2][4], lrow[2][4];
#pragma unroll
  for (int m = 0; m < 2; ++m)
#pragma unroll
    for (int r = 0; r < 4; ++r) { mrow[m][r] = -3e38f; lrow[m][r] = 0.f; }

  const float cl = 0.125f * 1.44269504089f;  // hd^-0.5 * log2(e)

  // staging geometry
  const int krow = lane >> 3;       // row within 8-row chunk (K staging)
  const int kch = lane & 7;         // 16B chunk within 128B row
  const int vkv = (tid & 31) * 2;   // V: kv pair
  const int vd0 = (tid >> 5) * 8;   // V: d chunk

  for (int kv0 = 0; kv0 < T_SZ; kv0 += KVB) {
    __syncthreads();
    // K tile via global_load_lds, source pre-swizzled so swizzled reads are linear
#pragma unroll
    for (int i = 0; i < 2; ++i) {
      const int c = wid + 4 * i;
      const int row = c * 8 + krow;
      const int sch = kch ^ (row & 7);
      gld_lds16(Kl + c * 1024, &K[base + (kv0 + row) * D_SZ + sch * 8]);
    }
    // V tile, reg-staged TRANSPOSED into Vl[d][kv] (packed pair writes)
    s16x8 v0 = *(const s16x8*)&V[base + (kv0 + vkv) * D_SZ + vd0];
    s16x8 v1 = *(const s16x8*)&V[base + (kv0 + vkv + 1) * D_SZ + vd0];
#pragma unroll
    for (int j = 0; j < 8; ++j) {
      const int d = vd0 + j;
      unsigned int pk = (unsigned int)(unsigned short)v0[j] |
                        ((unsigned int)(unsigned short)v1[j] << 16);
      *(unsigned int*)(Vl + d * 128 + ((vkv * 2) ^ ((d & 7) << 4))) = pk;
    }
    __syncthreads();

    // S = Q K^T  (B-operand = K rows, contiguous d)
    f32x4 s[2][4] = {};
#pragma unroll
    for (int n = 0; n < 4; ++n) {
      const int kr = n * 16 + fr;
#pragma unroll
      for (int ks = 0; ks < 2; ++ks) {
        const s16x8 kf = *(const s16x8*)(Kl + kr * 128 + (((ks * 32 + kg) * 2) ^ ((kr & 7) << 4)));
#pragma unroll
        for (int m = 0; m < 2; ++m)
          s[m][n] = __builtin_amdgcn_mfma_f32_16x16x32_bf16(qf[m][ks], kf, s[m][n], 0, 0, 0);
      }
    }

    // online softmax: rows live on (lane>>4, reg); cols on lane&15 + 16n
    float alpha[2][4];
#pragma unroll
    for (int m = 0; m < 2; ++m)
#pragma unroll
      for (int r = 0; r < 4; ++r) {
        float mx = fmaxf(fmaxf(s[m][0][r], s[m][1][r]), fmaxf(s[m][2][r], s[m][3][r]));
        mx = fmaxf(mx, __shfl_xor(mx, 1, 64));
        mx = fmaxf(mx, __shfl_xor(mx, 2, 64));
        mx = fmaxf(mx, __shfl_xor(mx, 4, 64));
        mx = fmaxf(mx, __shfl_xor(mx, 8, 64));
        const float mn = fmaxf(mrow[m][r], mx);
        alpha[m][r] = exp2f((mrow[m][r] - mn) * cl);
        mrow[m][r] = mn;
      }
#pragma unroll
    for (int m = 0; m < 2; ++m)
#pragma unroll
      for (int r = 0; r < 4; ++r) {
        float sum = 0.f;
#pragma unroll
        for (int n = 0; n < 4; ++n) {
          float p = exp2f((s[m][n][r] - mrow[m][r]) * cl);
          s[m][n][r] = p;
          sum += p;
        }
        sum += __shfl_xor(sum, 1, 64);
        sum += __shfl_xor(sum, 2, 64);
        sum += __shfl_xor(sum, 4, 64);
        sum += __shfl_xor(sum, 8, 64);
        lrow[m][r] = lrow[m][r] * alpha[m][r] + sum;
      }
#pragma unroll
    for (int m = 0; m < 2; ++m)
#pragma unroll
      for (int nd = 0; nd < 4; ++nd)
#pragma unroll
        for (int r = 0; r < 4; ++r)
          oacc[m][nd][r] *= alpha[m][r];

    // P -> per-wave LDS (bf16), swizzled; then read back as PV A-operand
    char* pw = Pl[wid];
#pragma unroll
    for (int m = 0; m < 2; ++m)
#pragma unroll
      for (int r = 0; r < 4; ++r) {
        const int q = m * 16 + ((lane >> 4) << 2) + r;
#pragma unroll
        for (int n = 0; n < 4; ++n) {
          const int kv = n * 16 + fr;
          *(unsigned short*)(pw + q * 128 + ((kv * 2) ^ ((q & 7) << 4))) = f2b(s[m][n][r]);
        }
      }

    // O += P V  (A = P rows contiguous kv; B = Vl rows = d, contiguous kv)
#pragma unroll
    for (int kk = 0; kk < 2; ++kk) {
      s16x8 pf[2];
#pragma unroll
      for (int m = 0; m < 2; ++m)
        pf[m] = *(const s16x8*)(pw + (m * 16 + fr) * 128 + (((kk * 32 + kg) * 2) ^ ((fr & 7) << 4)));
#pragma unroll
      for (int nd = 0; nd < 4; ++nd) {
        const int vrow = nd * 16 + fr;
        const s16x8 vf = *(const s16x8*)(Vl + vrow * 128 + (((kk * 32 + kg) * 2) ^ ((vrow & 7) << 4)));
#pragma unroll
        for (int m = 0; m < 2; ++m)
          oacc[m][nd] = __builtin_amdgcn_mfma_f32_16x16x32_bf16(pf[m], vf, oacc[m][nd], 0, 0, 0);
      }
    }
  }

  // epilogue: normalize and store bf16 [B*T, D]
#pragma unroll
  for (int m = 0; m < 2; ++m)
#pragma unroll
    for (int r = 0; r < 4; ++r) {
      const float inv = 1.0f / lrow[m][r];
      const int qrow = q0 + wq + m * 16 + ((lane >> 4) << 2) + r;
#pragma unroll
      for (int nd = 0; nd < 4; ++nd)
        O[base + qrow * D_SZ + nd * 16 + fr] = f2b(oacc[m][nd][r] * inv);
    }
}

// ---------- launch ----------
extern "C" void kernel_launch(void* const* d_in, const int* in_sizes, int n_in,
                              void* d_out, int out_size, void* d_ws, size_t ws_size,
                              hipStream_t stream) {
  const float* x  = (const float*)d_in[0];
  const float* Wq = (const float*)d_in[1];
  const float* Wk = (const float*)d_in[2];
  const float* Wv = (const float*)d_in[3];
  const float* Wo = (const float*)d_in[4];

  const int NTOK = B_SZ * T_SZ;         // 8192
  const int SZX = NTOK * D_SZ;          // 8M elems
  const int SZW = D_SZ * D_SZ;          // 1M elems

  unsigned short* ws  = (unsigned short*)d_ws;
  unsigned short* xb  = ws;             // x bf16; reused as attention output O
  unsigned short* wqb = xb + SZX;
  unsigned short* wkb = wqb + SZW;
  unsigned short* wvb = wkb + SZW;
  unsigned short* wob = wvb + SZW;
  unsigned short* Qb  = wob + SZW;
  unsigned short* Kb  = Qb + SZX;
  unsigned short* Vb  = Kb + SZX;       // total 36M elems = 72MB

  cast_kernel<<<SZX / 1024, 256, 0, stream>>>(x, xb, SZX / 4);
  cast_kernel<<<SZW / 1024, 256, 0, stream>>>(Wq, wqb, SZW / 4);
  cast_kernel<<<SZW / 1024, 256, 0, stream>>>(Wk, wkb, SZW / 4);
  cast_kernel<<<SZW / 1024, 256, 0, stream>>>(Wv, wvb, SZW / 4);
  cast_kernel<<<SZW / 1024, 256, 0, stream>>>(Wo, wob, SZW / 4);

  dim3 gg(NTOK / BM, D_SZ / BN);
  gemm_bt<unsigned short><<<gg, 256, 0, stream>>>(xb, wqb, Qb, NTOK, D_SZ, D_SZ);
  gemm_bt<unsigned short><<<gg, 256, 0, stream>>>(xb, wkb, Kb, NTOK, D_SZ, D_SZ);
  gemm_bt<unsigned short><<<gg, 256, 0, stream>>>(xb, wvb, Vb, NTOK, D_SZ, D_SZ);

  dim3 ga(T_SZ / QBLK, B_SZ * NH);
  attn_kernel<<<ga, 256, 0, stream>>>(Qb, Kb, Vb, xb);  // O overwrites xb (x is dead)

  gemm_bt<float><<<gg, 256, 0, stream>>>(xb, wob, (float*)d_out, NTOK, D_SZ, D_SZ);
}